// Round 3
// baseline (140.706 us; speedup 1.0000x reference)
//
#include <hip/hip_runtime.h>

// B = 4194304 rows, x is (B,4) fp32 row-major. Three 3->4->1 MLPs; output
// selected by sel = x[:,1] in {0,1,2}. Memory-bound: 83.9 MB traffic,
// ~13.3 us floor at 6.3 TB/s achievable.
//
// MEASUREMENT ROUND: the kernel is launched TWICE (idempotent — writes the
// same values both times, absmax unaffected). dur_us delta vs the 121.7 us
// single-launch baseline = kernel_cold + kernel_warm duration. This resolves
// whether the kernel is at the ~13.5 us traffic floor (scenario A: residual
// dur_us is harness re-poison fills, -> ROOFLINE) or at ~36 us (scenario B:
// ~2.3 TB/s, a fixable BW throttle). rocprof's top-k 5 view cannot show the
// kernel row (fills at 41.5 us dominate), so this is the only available probe.

#define ROWS 4

__global__ __launch_bounds__(256) void Program_72902774882571_kernel(
    const float* __restrict__ x,
    const float* __restrict__ Ws1, const float* __restrict__ bs1,
    const float* __restrict__ Ws2, const float* __restrict__ bs2,
    const float* __restrict__ Wu1, const float* __restrict__ bu1,
    const float* __restrict__ Wu2, const float* __restrict__ bu2,
    const float* __restrict__ Wd1, const float* __restrict__ bd1,
    const float* __restrict__ Wd2, const float* __restrict__ bd2,
    float* __restrict__ out, int n)
{
    const int base = blockIdx.x * (256 * ROWS) + threadIdx.x;

    // Issue all row loads first; they are independent.
    float4 xv[ROWS];
#pragma unroll
    for (int k = 0; k < ROWS; ++k) {
        const int i = base + k * 256;
        xv[k] = make_float4(0.f, -1.f, 0.f, 0.f);  // sel=-1 -> result 0
        if (i < n) xv[k] = reinterpret_cast<const float4*>(x)[i];
    }

    // Tiny MLP: h = relu(x3 @ W1 + b1) ; out = sigmoid(h @ W2 + b2)
    // W1 is (3,4) row-major, W2 is (4,1). Weight loads are wave-uniform
    // addresses -> scalarized + CSE'd across the 12 call sites by the compiler.
    auto net = [&](float x0, float x1, float x2,
                   const float* __restrict__ W1, const float* __restrict__ b1,
                   const float* __restrict__ W2, const float* __restrict__ b2) -> float {
        float acc = b2[0];
#pragma unroll
        for (int j = 0; j < 4; ++j) {
            float h = b1[j];
            h = fmaf(x0, W1[0 * 4 + j], h);
            h = fmaf(x1, W1[1 * 4 + j], h);
            h = fmaf(x2, W1[2 * 4 + j], h);
            h = fmaxf(h, 0.0f);          // relu
            acc = fmaf(h, W2[j], acc);
        }
        // sigmoid(a) = rcp(1 + exp2(-a*log2(e))) ; native trans ops, ~1ulp
        const float e = __builtin_amdgcn_exp2f(acc * -1.44269504088896340736f);
        return __builtin_amdgcn_rcpf(1.0f + e);
    };

#pragma unroll
    for (int k = 0; k < ROWS; ++k) {
        const int i = base + k * 256;
        if (i >= n) continue;   // never taken at B=4194304 (exact multiple)
        const float x0 = xv[k].x, x1 = xv[k].y, x2 = xv[k].z;

        const float os = net(x0, x1, x2, Ws1, bs1, Ws2, bs2);
        const float ou = net(x0, x1, x2, Wu1, bu1, Wu2, bu2);
        const float od = net(x0, x1, x2, Wd1, bd1, Wd2, bd2);

        // where(sel==0, s, where(sel==1, u, where(sel==2, d, 0)))
        float r = (x1 == 2.0f) ? od : 0.0f;
        r = (x1 == 1.0f) ? ou : r;
        r = (x1 == 0.0f) ? os : r;

        __builtin_nontemporal_store(r, &out[i]);  // 4 B/lane, coalesced
    }
}

extern "C" void kernel_launch(void* const* d_in, const int* in_sizes, int n_in,
                              void* d_out, int out_size, void* d_ws, size_t ws_size,
                              hipStream_t stream) {
    const float* x   = (const float*)d_in[0];
    const float* Ws1 = (const float*)d_in[1];
    const float* bs1 = (const float*)d_in[2];
    const float* Ws2 = (const float*)d_in[3];
    const float* bs2 = (const float*)d_in[4];
    const float* Wu1 = (const float*)d_in[5];
    const float* bu1 = (const float*)d_in[6];
    const float* Wu2 = (const float*)d_in[7];
    const float* bu2 = (const float*)d_in[8];
    const float* Wd1 = (const float*)d_in[9];
    const float* bd1 = (const float*)d_in[10];
    const float* Wd2 = (const float*)d_in[11];
    const float* bd2 = (const float*)d_in[12];

    const int n = out_size;  // B = 4194304 rows
    const int block = 256;
    const int rows_per_block = block * ROWS;                 // 1024
    const int grid = (n + rows_per_block - 1) / rows_per_block;  // 4096 blocks

    // MEASUREMENT: two identical launches. Idempotent -> correctness intact.
    // dur_us - 121.7 = kernel_cold + kernel_warm.
    Program_72902774882571_kernel<<<grid, block, 0, stream>>>(
        x, Ws1, bs1, Ws2, bs2, Wu1, bu1, Wu2, bu2, Wd1, bd1, Wd2, bd2,
        (float*)d_out, n);
    Program_72902774882571_kernel<<<grid, block, 0, stream>>>(
        x, Ws1, bs1, Ws2, bs2, Wu1, bu1, Wu2, bu2, Wd1, bd1, Wd2, bd2,
        (float*)d_out, n);
}

// Round 4
// 131.947 us; speedup vs baseline: 1.0664x; 1.0664x over previous
//
#include <hip/hip_runtime.h>

// B = 4194304 rows, x is (B,4) fp32 row-major. Three 3->4->1 MLPs; output
// selected by sel = x[:,1] in {0,1,2}. Memory-bound-ish: 83.9 MB traffic,
// 13.3 us ideal floor at 6.3 TB/s; measured kernel ~19-21 us (double-launch
// probe R3: warm launch = +19.0 us), i.e. issue/stall-bound above the floor.
//
// This revision:
//  - SELECT-FIRST: pick the 21 weights of the selected net via per-row
//    cndmask (2 per weight, compares hoisted), then evaluate ONE net.
//    Bit-identical to computing the selected net directly (same FMA order,
//    same exp/rcp), but cuts transcendentals 3x -> 1x and drops ~2 nets of
//    FMA work for ~1 net of cndmask work (~22% compute-cycle cut).
//  - Non-temporal float4 loads of x (read-once stream; no L2/L3 pollution).
//  - ROWS=4, all loads issued up-front; NT stores; single launch (probe
//    from R3 reverted).

#define ROWS 4

typedef float fvec4 __attribute__((ext_vector_type(4)));

__global__ __launch_bounds__(256) void Program_72902774882571_kernel(
    const float* __restrict__ x,
    const float* __restrict__ Ws1, const float* __restrict__ bs1,
    const float* __restrict__ Ws2, const float* __restrict__ bs2,
    const float* __restrict__ Wu1, const float* __restrict__ bu1,
    const float* __restrict__ Wu2, const float* __restrict__ bu2,
    const float* __restrict__ Wd1, const float* __restrict__ bd1,
    const float* __restrict__ Wd2, const float* __restrict__ bd2,
    float* __restrict__ out, int n)
{
    const int base = blockIdx.x * (256 * ROWS) + threadIdx.x;

    // Issue all row loads first; independent -> 4x16B in flight per lane.
    fvec4 xv[ROWS];
#pragma unroll
    for (int k = 0; k < ROWS; ++k) {
        const int i = base + k * 256;
        xv[k] = (fvec4){0.f, -1.f, 0.f, 0.f};   // sel=-1 -> result 0
        if (i < n)
            xv[k] = __builtin_nontemporal_load(reinterpret_cast<const fvec4*>(x) + i);
    }

#pragma unroll
    for (int k = 0; k < ROWS; ++k) {
        const int i = base + k * 256;
        if (i >= n) continue;   // never taken at B=4194304 (exact multiple)
        const float x0 = xv[k][0], x1 = xv[k][1], x2 = xv[k][2];

        // Per-row selector masks (computed once, reused by all 21 selects).
        const bool is_s = (x1 == 0.0f);
        const bool is_u = (x1 == 1.0f);
        const bool is_d = (x1 == 2.0f);

        // 3-way select: 2 cndmask per weight. Weight operands are wave-
        // uniform s_load results; cndmask mixes them per-lane.
        auto pick = [&](float s, float u, float d) -> float {
            return is_s ? s : (is_u ? u : d);
        };

        // ONE net with the selected weights: h = relu(x3 @ W1 + b1),
        // o = sigmoid(h @ W2 + b2). W1 (3,4) row-major, W2 (4,1).
        float acc = pick(bs2[0], bu2[0], bd2[0]);
#pragma unroll
        for (int j = 0; j < 4; ++j) {
            float h = pick(bs1[j], bu1[j], bd1[j]);
            h = fmaf(x0, pick(Ws1[0 * 4 + j], Wu1[0 * 4 + j], Wd1[0 * 4 + j]), h);
            h = fmaf(x1, pick(Ws1[1 * 4 + j], Wu1[1 * 4 + j], Wd1[1 * 4 + j]), h);
            h = fmaf(x2, pick(Ws1[2 * 4 + j], Wu1[2 * 4 + j], Wd1[2 * 4 + j]), h);
            h = fmaxf(h, 0.0f);          // relu
            acc = fmaf(h, pick(Ws2[j], Wu2[j], Wd2[j]), acc);
        }
        // sigmoid(a) = rcp(1 + exp2(-a*log2(e))) ; native trans ops, ~1ulp
        const float e = __builtin_amdgcn_exp2f(acc * -1.44269504088896340736f);
        const float o = __builtin_amdgcn_rcpf(1.0f + e);

        // Zero for sel outside {0,1,2} (matches reference where-chain).
        const float r = (is_s | is_u | is_d) ? o : 0.0f;

        __builtin_nontemporal_store(r, &out[i]);  // 4 B/lane, coalesced
    }
}

extern "C" void kernel_launch(void* const* d_in, const int* in_sizes, int n_in,
                              void* d_out, int out_size, void* d_ws, size_t ws_size,
                              hipStream_t stream) {
    const float* x   = (const float*)d_in[0];
    const float* Ws1 = (const float*)d_in[1];
    const float* bs1 = (const float*)d_in[2];
    const float* Ws2 = (const float*)d_in[3];
    const float* bs2 = (const float*)d_in[4];
    const float* Wu1 = (const float*)d_in[5];
    const float* bu1 = (const float*)d_in[6];
    const float* Wu2 = (const float*)d_in[7];
    const float* bu2 = (const float*)d_in[8];
    const float* Wd1 = (const float*)d_in[9];
    const float* bd1 = (const float*)d_in[10];
    const float* Wd2 = (const float*)d_in[11];
    const float* bd2 = (const float*)d_in[12];

    const int n = out_size;  // B = 4194304 rows
    const int block = 256;
    const int rows_per_block = block * ROWS;                 // 1024
    const int grid = (n + rows_per_block - 1) / rows_per_block;  // 4096 blocks

    Program_72902774882571_kernel<<<grid, block, 0, stream>>>(
        x, Ws1, bs1, Ws2, bs2, Wu1, bu1, Wu2, bu2, Wd1, bd1, Wd2, bd2,
        (float*)d_out, n);
}

// Round 5
// 124.473 us; speedup vs baseline: 1.1304x; 1.0600x over previous
//
#include <hip/hip_runtime.h>

// B = 4194304 rows, x is (B,4) fp32 row-major. Three 3->4->1 MLPs; output
// selected by sel = x[:,1] in {0,1,2}. Traffic floor: 67.1 MB x-read +
// 16.8 MB out-write = 83.9 MB -> 13.3 us at 6.3 TB/s. R3 double-launch
// probe: warm kernel ~19 us -> issue-bound above the floor.
//
// This revision (vs R2 best=121.68):
//  - x1-FOLD: sel=x1 in {0,1,2} exactly, and net_X's output is only used on
//    its own branch. Compute each net as if x1 == its branch value:
//    bu1' = bu1 + Wu1[1][:], bd1' = bd1 + 2*Wd1[1][:] (folded once/thread).
//    First layer: 3 FMA -> 2 FMA per hidden unit. Row FMAs 60 -> 40.
//  - ONE sigmoid: select the pre-sigmoid accumulator (3 cndmask on VGPR
//    values - no SGPR-operand hazard), then a single exp2+rcp. Trans 6->2.
//  - ROWS=8 (2048 blocks): 8x16B loads in flight/lane, less prologue/wave.
//  - Plain (cached) x loads - R4 showed NT loads regress. NT stores kept.

#define ROWS 8

typedef float fvec4 __attribute__((ext_vector_type(4)));

template <bool EXACT>
__global__ __launch_bounds__(256) void Program_72902774882571_kernel(
    const float* __restrict__ x,
    const float* __restrict__ Ws1, const float* __restrict__ bs1,
    const float* __restrict__ Ws2, const float* __restrict__ bs2,
    const float* __restrict__ Wu1, const float* __restrict__ bu1,
    const float* __restrict__ Wu2, const float* __restrict__ bu2,
    const float* __restrict__ Wd1, const float* __restrict__ bd1,
    const float* __restrict__ Wd2, const float* __restrict__ bd2,
    float* __restrict__ out, int n)
{
    const int base = blockIdx.x * (256 * ROWS) + threadIdx.x;

    // Issue all row loads first; independent -> 8x16B in flight per lane.
    fvec4 xv[ROWS];
#pragma unroll
    for (int k = 0; k < ROWS; ++k) {
        const int i = base + k * 256;
        if (EXACT || i < n)
            xv[k] = reinterpret_cast<const fvec4*>(x)[i];
        else
            xv[k] = (fvec4){0.f, -1.f, 0.f, 0.f};  // sel=-1 -> result 0
    }

    // Fold x1 into first-layer bias per branch (x1 = 0 / 1 / 2 resp.).
    // fmaf(1,w,b)=w+b and fmaf(2,w,b) are single-rounded, same as in-net fma.
    float bup[4], bdp[4];
#pragma unroll
    for (int j = 0; j < 4; ++j) {
        bup[j] = bu1[j] + Wu1[4 + j];
        bdp[j] = fmaf(2.0f, Wd1[4 + j], bd1[j]);
    }

#pragma unroll
    for (int k = 0; k < ROWS; ++k) {
        const int i = base + k * 256;
        if (!EXACT && i >= n) continue;
        const float x0 = xv[k][0], x1 = xv[k][1], x2 = xv[k][2];

        // W1 (3,4) row-major: row r elem j = W1[r*4+j]. W2 is (4,1).
        float as = bs2[0], au = bu2[0], ad = bd2[0];
#pragma unroll
        for (int j = 0; j < 4; ++j) {
            const float hs = fmaf(x0, Ws1[j], fmaf(x2, Ws1[8 + j], bs1[j]));
            const float hu = fmaf(x0, Wu1[j], fmaf(x2, Wu1[8 + j], bup[j]));
            const float hd = fmaf(x0, Wd1[j], fmaf(x2, Wd1[8 + j], bdp[j]));
            as = fmaf(fmaxf(hs, 0.f), Ws2[j], as);
            au = fmaf(fmaxf(hu, 0.f), Wu2[j], au);
            ad = fmaf(fmaxf(hd, 0.f), Wd2[j], ad);
        }

        // Select pre-sigmoid accumulator (VGPR cndmask chain), one sigmoid.
        float a = (x1 == 2.0f) ? ad : 0.0f;
        a = (x1 == 1.0f) ? au : a;
        a = (x1 == 0.0f) ? as : a;
        const float e = __builtin_amdgcn_exp2f(a * -1.44269504088896340736f);
        float r = __builtin_amdgcn_rcpf(1.0f + e);
        // Zero when sel outside {0,1,2} (matches reference where-chain).
        const bool valid = (x1 == 0.0f) | (x1 == 1.0f) | (x1 == 2.0f);
        r = valid ? r : 0.0f;

        __builtin_nontemporal_store(r, &out[i]);  // 4 B/lane, coalesced
    }
}

extern "C" void kernel_launch(void* const* d_in, const int* in_sizes, int n_in,
                              void* d_out, int out_size, void* d_ws, size_t ws_size,
                              hipStream_t stream) {
    const float* x   = (const float*)d_in[0];
    const float* Ws1 = (const float*)d_in[1];
    const float* bs1 = (const float*)d_in[2];
    const float* Ws2 = (const float*)d_in[3];
    const float* bs2 = (const float*)d_in[4];
    const float* Wu1 = (const float*)d_in[5];
    const float* bu1 = (const float*)d_in[6];
    const float* Wu2 = (const float*)d_in[7];
    const float* bu2 = (const float*)d_in[8];
    const float* Wd1 = (const float*)d_in[9];
    const float* bd1 = (const float*)d_in[10];
    const float* Wd2 = (const float*)d_in[11];
    const float* bd2 = (const float*)d_in[12];

    const int n = out_size;  // B = 4194304 rows
    const int block = 256;
    const int rows_per_block = block * ROWS;                      // 2048
    const int grid = (n + rows_per_block - 1) / rows_per_block;   // 2048 blocks

    if (n % rows_per_block == 0) {
        Program_72902774882571_kernel<true><<<grid, block, 0, stream>>>(
            x, Ws1, bs1, Ws2, bs2, Wu1, bu1, Wu2, bu2, Wd1, bd1, Wd2, bd2,
            (float*)d_out, n);
    } else {
        Program_72902774882571_kernel<false><<<grid, block, 0, stream>>>(
            x, Ws1, bs1, Ws2, bs2, Wu1, bu1, Wu2, bu2, Wd1, bd1, Wd2, bd2,
            (float*)d_out, n);
    }
}

// Round 6
// 121.005 us; speedup vs baseline: 1.1628x; 1.0287x over previous
//
#include <hip/hip_runtime.h>

// B = 4194304 rows, x is (B,4) fp32 row-major. Three 3->4->1 MLPs; output
// selected by sel = x[:,1] in {0,1,2}. Memory-bound: 83.9 MB traffic,
// ~13.3 us floor at 6.3 TB/s achievable.
//
// FINAL (revert to best measured config, R2 = 121.68 us):
//  - ROWS=4 per thread, all 4 float4 row-loads issued before any compute
//    (independent -> 4x in-flight bytes per wave). Lane-contiguous float4
//    (16 B/lane, 4 KiB/wave) = perfect coalescing.
//  - sigmoid via native v_exp_f32 (exp2 formulation) + v_rcp_f32 (tol 1e-2).
//  - non-temporal stores; PLAIN cached loads (NT loads regressed, R4).
//  - Session evidence: kernel itself ~19 us (R3 double-launch probe) of the
//    ~122 us timed region; the rest is harness re-poison fills (268 MB at
//    77-82% HBM peak). Compute cuts (R4: select-first, R5: x1-fold + single
//    sigmoid + ROWS=8) regressed +10.3 / +2.8 us -> kernel residual above
//    the 13.3 us traffic floor is ramp/tail + stream turnaround, not VALU.

#define ROWS 4

__global__ __launch_bounds__(256) void Program_72902774882571_kernel(
    const float* __restrict__ x,
    const float* __restrict__ Ws1, const float* __restrict__ bs1,
    const float* __restrict__ Ws2, const float* __restrict__ bs2,
    const float* __restrict__ Wu1, const float* __restrict__ bu1,
    const float* __restrict__ Wu2, const float* __restrict__ bu2,
    const float* __restrict__ Wd1, const float* __restrict__ bd1,
    const float* __restrict__ Wd2, const float* __restrict__ bd2,
    float* __restrict__ out, int n)
{
    const int base = blockIdx.x * (256 * ROWS) + threadIdx.x;

    // Issue all row loads first; they are independent.
    float4 xv[ROWS];
#pragma unroll
    for (int k = 0; k < ROWS; ++k) {
        const int i = base + k * 256;
        xv[k] = make_float4(0.f, -1.f, 0.f, 0.f);  // sel=-1 -> result 0
        if (i < n) xv[k] = reinterpret_cast<const float4*>(x)[i];
    }

    // Tiny MLP: h = relu(x3 @ W1 + b1) ; out = sigmoid(h @ W2 + b2)
    // W1 is (3,4) row-major, W2 is (4,1). Weight loads are wave-uniform
    // addresses -> scalarized + CSE'd across the 12 call sites by the compiler.
    auto net = [&](float x0, float x1, float x2,
                   const float* __restrict__ W1, const float* __restrict__ b1,
                   const float* __restrict__ W2, const float* __restrict__ b2) -> float {
        float acc = b2[0];
#pragma unroll
        for (int j = 0; j < 4; ++j) {
            float h = b1[j];
            h = fmaf(x0, W1[0 * 4 + j], h);
            h = fmaf(x1, W1[1 * 4 + j], h);
            h = fmaf(x2, W1[2 * 4 + j], h);
            h = fmaxf(h, 0.0f);          // relu
            acc = fmaf(h, W2[j], acc);
        }
        // sigmoid(a) = rcp(1 + exp2(-a*log2(e))) ; native trans ops, ~1ulp
        const float e = __builtin_amdgcn_exp2f(acc * -1.44269504088896340736f);
        return __builtin_amdgcn_rcpf(1.0f + e);
    };

#pragma unroll
    for (int k = 0; k < ROWS; ++k) {
        const int i = base + k * 256;
        if (i >= n) continue;   // never taken at B=4194304 (exact multiple)
        const float x0 = xv[k].x, x1 = xv[k].y, x2 = xv[k].z;

        const float os = net(x0, x1, x2, Ws1, bs1, Ws2, bs2);
        const float ou = net(x0, x1, x2, Wu1, bu1, Wu2, bu2);
        const float od = net(x0, x1, x2, Wd1, bd1, Wd2, bd2);

        // where(sel==0, s, where(sel==1, u, where(sel==2, d, 0)))
        float r = (x1 == 2.0f) ? od : 0.0f;
        r = (x1 == 1.0f) ? ou : r;
        r = (x1 == 0.0f) ? os : r;

        __builtin_nontemporal_store(r, &out[i]);  // 4 B/lane, coalesced
    }
}

extern "C" void kernel_launch(void* const* d_in, const int* in_sizes, int n_in,
                              void* d_out, int out_size, void* d_ws, size_t ws_size,
                              hipStream_t stream) {
    const float* x   = (const float*)d_in[0];
    const float* Ws1 = (const float*)d_in[1];
    const float* bs1 = (const float*)d_in[2];
    const float* Ws2 = (const float*)d_in[3];
    const float* bs2 = (const float*)d_in[4];
    const float* Wu1 = (const float*)d_in[5];
    const float* bu1 = (const float*)d_in[6];
    const float* Wu2 = (const float*)d_in[7];
    const float* bu2 = (const float*)d_in[8];
    const float* Wd1 = (const float*)d_in[9];
    const float* bd1 = (const float*)d_in[10];
    const float* Wd2 = (const float*)d_in[11];
    const float* bd2 = (const float*)d_in[12];

    const int n = out_size;  // B = 4194304 rows
    const int block = 256;
    const int rows_per_block = block * ROWS;                 // 1024
    const int grid = (n + rows_per_block - 1) / rows_per_block;  // 4096 blocks

    Program_72902774882571_kernel<<<grid, block, 0, stream>>>(
        x, Ws1, bs1, Ws2, bs2, Wu1, bu1, Wu2, bu2, Wd1, bd1, Wd2, bd2,
        (float*)d_out, n);
}